// Round 3
// baseline (1191.033 us; speedup 1.0000x reference)
//
#include <hip/hip_runtime.h>

// RSSM fused forward: one persistent kernel, 256 blocks x 256 threads.
// Block = 8 batch elements x 32 row-slots; lane = e + 8*r (r = slot&7).
// h[32] lives in registers per lane; weights in LDS with conflict-free pads.
// Straight-through z is exactly 8-sparse (one-hot positions carry p+(1-p),
// off-hot positions are IEEE-exact +0), exploited in gi (Wih@za) and dec.
// R1: software-pipelined input loads (prefetch t+1's x/gumbel/a during t).
// R2: fix vhn fma order (ascending k); nontemporal output stores.

#define TT 256
#define NB 2048
#define HH 32
#define ZD 64
#define XDm 10
#define ADm 4
#define GIN 68   // ZD + ADm
#define EIN 42   // HH + XDm

// LDS strides (floats), chosen for 16B row alignment + conflict-free multicast
#define SWHH_S 36
#define SWIH_S 97
#define SENC_S 44
#define SDYN_S 36
#define SDEC_S 100
#define SH_S   36
#define SZ_S   68

// output offsets (floats) in return order: x_logits, r_loc, c_logits, zpl, zpo
#define OFF_X   0ul
#define OFF_R   5242880ul
#define OFF_C   5767168ul
#define OFF_ZPL 6291456ul
#define OFF_ZPO 39845888ul

__device__ __forceinline__ float sigmoid_f(float v) { return 1.f / (1.f + __expf(-v)); }
__device__ __forceinline__ void nt_store(float* p, float v) { __builtin_nontemporal_store(v, p); }

extern "C" __global__ void __launch_bounds__(256)
rssm_fused(const float* __restrict__ x, const float* __restrict__ a,
           const float* __restrict__ h0, const float* __restrict__ gum,
           const float* __restrict__ encW, const float* __restrict__ encB,
           const float* __restrict__ Wih, const float* __restrict__ Whh,
           const float* __restrict__ bih, const float* __restrict__ bhh,
           const float* __restrict__ decW, const float* __restrict__ decB,
           const float* __restrict__ dynW, const float* __restrict__ dynB,
           const float* __restrict__ rewW, const float* __restrict__ conW,
           const float* __restrict__ conB, float* __restrict__ out)
{
    __shared__ __align__(16) float sWhh[96 * SWHH_S];
    __shared__ float sWih[GIN * SWIH_S];            // transposed: [col][row]
    __shared__ __align__(16) float sEnc[64 * SENC_S];
    __shared__ __align__(16) float sDyn[64 * SDYN_S];
    __shared__ __align__(16) float sDec[10 * SDEC_S];
    __shared__ float sBih[96], sBhh[96], sEncB[64], sDynB[64], sDecB[16];
    __shared__ float sRew[32], sCon[32], sConB;
    __shared__ __align__(16) float sH[8 * SH_S];    // h exchange
    __shared__ float sVal[8 * 9];                   // sparse z values [e][s]
    __shared__ int   sIdx[8 * 9];                   // sparse z indices [e][s]
    __shared__ float sZL[8 * SZ_S];                 // prior logits staging
    __shared__ float sZP[8 * SZ_S];                 // post logits staging

    const int tid = threadIdx.x;

    // ---- stage weights into LDS ----
    for (int i = tid; i < 96 * HH; i += 256) { int j = i >> 5, k = i & 31; sWhh[j * SWHH_S + k] = Whh[i]; }
    for (int i = tid; i < 96 * GIN; i += 256) { int j = i / GIN, c = i - j * GIN; sWih[c * SWIH_S + j] = Wih[i]; }
    for (int i = tid; i < 64 * EIN; i += 256) { int j = i / EIN, c = i - j * EIN; sEnc[j * SENC_S + c] = encW[i]; }
    for (int i = tid; i < 64 * HH; i += 256) { int j = i >> 5, k = i & 31; sDyn[j * SDYN_S + k] = dynW[i]; }
    for (int i = tid; i < 10 * 96; i += 256) { int j = i / 96, c = i - j * 96; sDec[j * SDEC_S + c] = decW[i]; }
    if (tid < 96) { sBih[tid] = bih[tid]; sBhh[tid] = bhh[tid]; }
    if (tid >= 96 && tid < 160) { sEncB[tid - 96] = encB[tid - 96]; sDynB[tid - 96] = dynB[tid - 96]; }
    if (tid >= 160 && tid < 170) sDecB[tid - 160] = decB[tid - 160];
    if (tid >= 192 && tid < 224) sRew[tid - 192] = rewW[tid - 192];
    if (tid >= 224) sCon[tid - 224] = conW[tid - 224];
    if (tid == 170) sConB = conB[0];

    const int e    = tid & 7;        // element within block
    const int slot = tid >> 3;       // 0..31 row-slot
    const int w    = slot >> 3;      // wave index 0..3 (== tid>>6)
    const int r    = slot & 7;       // position within group
    const int n0   = blockIdx.x * 8;
    const int n    = n0 + e;

    // ---- stage h0 ----
    { int ee = tid >> 5, k = tid & 31; sH[ee * SH_S + k] = h0[(n0 + ee) * HH + k]; }
    __syncthreads();

    float h[HH];
#pragma unroll
    for (int k = 0; k < HH; k += 4) {
        float4 v = *(const float4*)&sH[e * SH_S + k];
        h[k] = v.x; h[k + 1] = v.y; h[k + 2] = v.z; h[k + 3] = v.w;
    }
    float h_own = sH[e * SH_S + slot];   // == h[slot], avoids runtime reg indexing

    const float* xptr = x   + (size_t)n * XDm;
    const float* gptr = gum + (size_t)n * ZD;
    const float* aptr = a   + (size_t)n * ADm;

    // ---- prime the input pipeline: cur = {x[0], gumbel[0]}, ap unused at t=0 ----
    float et[XDm], ap[ADm];
    float g1, g2;
#pragma unroll
    for (int m = 0; m < XDm; ++m) et[m] = xptr[m];
    g1 = gptr[8 * w + r];
    g2 = gptr[32 + 8 * w + r];
#pragma unroll
    for (int m = 0; m < ADm; ++m) ap[m] = 0.f;

#pragma unroll 1
    for (int t = 0; t < TT; ++t) {
        // ---- prefetch t+1 inputs (consumed next iteration; hides HBM latency) ----
        float etn[XDm], apn[ADm], g1n = 0.f, g2n = 0.f;
        if (t + 1 < TT) {
            const float* xp = xptr + (size_t)(t + 1) * (NB * XDm);
#pragma unroll
            for (int m = 0; m < XDm; ++m) etn[m] = xp[m];
            const float* gp = gptr + (size_t)(t + 1) * (NB * ZD);
            g1n = gp[8 * w + r];
            g2n = gp[32 + 8 * w + r];
            const float* app = aptr + (size_t)t * (NB * ADm);   // a[t], used by GRU at t+1
#pragma unroll
            for (int m = 0; m < ADm; ++m) apn[m] = app[m];
        } else {
#pragma unroll
            for (int m = 0; m < XDm; ++m) etn[m] = 0.f;
#pragma unroll
            for (int m = 0; m < ADm; ++m) apn[m] = 0.f;
        }

        // ---- GRU step (t >= 1): h_t = GRU([z_{t-1}, a_{t-1}], h_{t-1}) ----
        if (t > 0) {
            float vhr = 0.f, vhz = 0.f, vhn = 0.f;
            const float4* wr = (const float4*)&sWhh[slot * SWHH_S];
            const float4* wz = (const float4*)&sWhh[(32 + slot) * SWHH_S];
            const float4* wn = (const float4*)&sWhh[(64 + slot) * SWHH_S];
#pragma unroll
            for (int kk = 0; kk < 8; ++kk) {
                float4 wa = wr[kk], wb = wz[kk], wc = wn[kk];
                vhr = fmaf(wa.x, h[4 * kk], vhr); vhr = fmaf(wa.y, h[4 * kk + 1], vhr);
                vhr = fmaf(wa.z, h[4 * kk + 2], vhr); vhr = fmaf(wa.w, h[4 * kk + 3], vhr);
                vhz = fmaf(wb.x, h[4 * kk], vhz); vhz = fmaf(wb.y, h[4 * kk + 1], vhz);
                vhz = fmaf(wb.z, h[4 * kk + 2], vhz); vhz = fmaf(wb.w, h[4 * kk + 3], vhz);
                vhn = fmaf(wc.x, h[4 * kk], vhn); vhn = fmaf(wc.y, h[4 * kk + 1], vhn);
                vhn = fmaf(wc.z, h[4 * kk + 2], vhn); vhn = fmaf(wc.w, h[4 * kk + 3], vhn);
            }
            float vir = 0.f, viz = 0.f, vin = 0.f;
#pragma unroll
            for (int s = 0; s < 8; ++s) {               // sparse z part of gi
                int   c = 8 * s + sIdx[e * 9 + s];
                float v = sVal[e * 9 + s];
                const float* wc = &sWih[c * SWIH_S];
                vir = fmaf(wc[slot], v, vir);
                viz = fmaf(wc[32 + slot], v, viz);
                vin = fmaf(wc[64 + slot], v, vin);
            }
#pragma unroll
            for (int m = 0; m < ADm; ++m) {             // action part of gi
                const float* wc = &sWih[(64 + m) * SWIH_S];
                float av = ap[m];
                vir = fmaf(wc[slot], av, vir);
                viz = fmaf(wc[32 + slot], av, viz);
                vin = fmaf(wc[64 + slot], av, vin);
            }
            float gir = vir + sBih[slot],      ghr = vhr + sBhh[slot];
            float giz = viz + sBih[32 + slot], ghz = vhz + sBhh[32 + slot];
            float gnn = vin + sBih[64 + slot], ghn = vhn + sBhh[64 + slot];
            float rg = sigmoid_f(gir + ghr);
            float zg = sigmoid_f(giz + ghz);
            float ng = tanhf(gnn + rg * ghn);
            float hn_ = (1.f - zg) * ng + zg * h_own;   // un-fused, matches ref order
            sH[e * SH_S + slot] = hn_;
        }
        __syncthreads();   // barrier A: h_new ready; prev-iter LDS reads done
        if (t > 0) {
#pragma unroll
            for (int k = 0; k < HH; k += 4) {
                float4 v = *(const float4*)&sH[e * SH_S + k];
                h[k] = v.x; h[k + 1] = v.y; h[k + 2] = v.z; h[k + 3] = v.w;
            }
            h_own = sH[e * SH_S + slot];
        }

        // ---- encoder: zl = enc_W @ [h ; e_t] + enc_b (slot rows j and 32+j) ----
        float z1 = 0.f, z2 = 0.f;
        {
            const float4* e1 = (const float4*)&sEnc[slot * SENC_S];
            const float4* e2 = (const float4*)&sEnc[(32 + slot) * SENC_S];
#pragma unroll
            for (int kk = 0; kk < 8; ++kk) {
                float4 wa = e1[kk], wb = e2[kk];
                z1 = fmaf(wa.x, h[4 * kk], z1); z1 = fmaf(wa.y, h[4 * kk + 1], z1);
                z1 = fmaf(wa.z, h[4 * kk + 2], z1); z1 = fmaf(wa.w, h[4 * kk + 3], z1);
                z2 = fmaf(wb.x, h[4 * kk], z2); z2 = fmaf(wb.y, h[4 * kk + 1], z2);
                z2 = fmaf(wb.z, h[4 * kk + 2], z2); z2 = fmaf(wb.w, h[4 * kk + 3], z2);
            }
            const float* e1s = &sEnc[slot * SENC_S + 32];
            const float* e2s = &sEnc[(32 + slot) * SENC_S + 32];
#pragma unroll
            for (int m = 0; m < XDm; ++m) {
                z1 = fmaf(e1s[m], et[m], z1);
                z2 = fmaf(e2s[m], et[m], z2);
            }
            z1 += sEncB[slot];
            z2 += sEncB[32 + slot];
        }

        // ---- straight-through gumbel sample per group (wave w owns groups w, 4+w) ----
        float mx1 = z1, mx2 = z2;
#pragma unroll
        for (int d = 8; d < 64; d <<= 1) {
            mx1 = fmaxf(mx1, __shfl_xor(mx1, d));
            mx2 = fmaxf(mx2, __shfl_xor(mx2, d));
        }
        float key1 = z1 + g1; int ki1 = r;
        float key2 = z2 + g2; int ki2 = r;
#pragma unroll
        for (int d = 8; d < 64; d <<= 1) {
            float ok = __shfl_xor(key1, d); int oi = __shfl_xor(ki1, d);
            if (ok > key1 || (ok == key1 && oi < ki1)) { key1 = ok; ki1 = oi; }
            float ok2 = __shfl_xor(key2, d); int oi2 = __shfl_xor(ki2, d);
            if (ok2 > key2 || (ok2 == key2 && oi2 < ki2)) { key2 = ok2; ki2 = oi2; }
        }
        float p1 = __expf(z1 - mx1), p2 = __expf(z2 - mx2);
        float s1 = p1, s2 = p2;
#pragma unroll
        for (int d = 8; d < 64; d <<= 1) {
            s1 += __shfl_xor(s1, d);
            s2 += __shfl_xor(s2, d);
        }
        float pk1 = __shfl(p1, e + 8 * ki1) / s1;   // prob at argmax position
        float pk2 = __shfl(p2, e + 8 * ki2) / s2;
        if (r == 0) {
            sVal[e * 9 + w]     = pk1 + (1.f - pk1); sIdx[e * 9 + w]     = ki1;
            sVal[e * 9 + 4 + w] = pk2 + (1.f - pk2); sIdx[e * 9 + 4 + w] = ki2;
        }
        sZL[e * SZ_S + slot]      = z1;
        sZL[e * SZ_S + 32 + slot] = z2;

        // ---- dynamics head: z_post = dyn_W @ h + dyn_b ----
        {
            float d1 = 0.f, d2 = 0.f;
            const float4* q1 = (const float4*)&sDyn[slot * SDYN_S];
            const float4* q2 = (const float4*)&sDyn[(32 + slot) * SDYN_S];
#pragma unroll
            for (int kk = 0; kk < 8; ++kk) {
                float4 wa = q1[kk], wb = q2[kk];
                d1 = fmaf(wa.x, h[4 * kk], d1); d1 = fmaf(wa.y, h[4 * kk + 1], d1);
                d1 = fmaf(wa.z, h[4 * kk + 2], d1); d1 = fmaf(wa.w, h[4 * kk + 3], d1);
                d2 = fmaf(wb.x, h[4 * kk], d2); d2 = fmaf(wb.y, h[4 * kk + 1], d2);
                d2 = fmaf(wb.z, h[4 * kk + 2], d2); d2 = fmaf(wb.w, h[4 * kk + 3], d2);
            }
            sZP[e * SZ_S + slot]      = d1 + sDynB[slot];
            sZP[e * SZ_S + 32 + slot] = d2 + sDynB[32 + slot];
        }

        __syncthreads();   // barrier B: sZL/sZP/sVal/sIdx ready

        // ---- decoder / reward / continue heads (use current h and sparse z) ----
        if (slot < 10) {
            const float* dw = &sDec[slot * SDEC_S];
            float acc = 0.f;
#pragma unroll
            for (int k = 0; k < HH; ++k) acc = fmaf(dw[k], h[k], acc);
#pragma unroll
            for (int s = 0; s < 8; ++s)
                acc = fmaf(dw[32 + 8 * s + sIdx[e * 9 + s]], sVal[e * 9 + s], acc);
            acc += sDecB[slot];
            nt_store(&out[OFF_X + ((size_t)t * NB + n) * XDm + slot], acc);
        } else if (slot == 10) {
            float acc = 0.f;
#pragma unroll
            for (int k = 0; k < HH; ++k) acc = fmaf(sRew[k], h[k], acc);
            nt_store(&out[OFF_R + (size_t)t * NB + n], acc);
        } else if (slot == 11) {
            float acc = 0.f;
#pragma unroll
            for (int k = 0; k < HH; ++k) acc = fmaf(sCon[k], h[k], acc);
            nt_store(&out[OFF_C + (size_t)t * NB + n], acc + sConB);
        }

        // ---- coalesced z-logit output writes (stores issue late, fire-and-forget) ----
        {
            size_t rowbase = (size_t)t * NB + n0;
            int f1 = tid, f2 = tid + 256;
            int ee1 = f1 >> 6, c1 = f1 & 63, ee2 = f2 >> 6, c2 = f2 & 63;
            nt_store(&out[OFF_ZPL + (rowbase + ee1) * ZD + c1], sZL[ee1 * SZ_S + c1]);
            nt_store(&out[OFF_ZPL + (rowbase + ee2) * ZD + c2], sZL[ee2 * SZ_S + c2]);
            nt_store(&out[OFF_ZPO + (rowbase + ee1) * ZD + c1], sZP[ee1 * SZ_S + c1]);
            nt_store(&out[OFF_ZPO + (rowbase + ee2) * ZD + c2], sZP[ee2 * SZ_S + c2]);
        }

        // ---- rotate input pipeline ----
#pragma unroll
        for (int m = 0; m < XDm; ++m) et[m] = etn[m];
#pragma unroll
        for (int m = 0; m < ADm; ++m) ap[m] = apn[m];
        g1 = g1n; g2 = g2n;
    }
}

extern "C" void kernel_launch(void* const* d_in, const int* in_sizes, int n_in,
                              void* d_out, int out_size, void* d_ws, size_t ws_size,
                              hipStream_t stream) {
    const float* x    = (const float*)d_in[0];
    const float* a    = (const float*)d_in[1];
    const float* h0   = (const float*)d_in[2];
    const float* gumb = (const float*)d_in[3];
    const float* encW = (const float*)d_in[4];
    const float* encB = (const float*)d_in[5];
    const float* Wih  = (const float*)d_in[6];
    const float* Whh  = (const float*)d_in[7];
    const float* bih  = (const float*)d_in[8];
    const float* bhh  = (const float*)d_in[9];
    const float* decW = (const float*)d_in[10];
    const float* decB = (const float*)d_in[11];
    const float* dynW = (const float*)d_in[12];
    const float* dynB = (const float*)d_in[13];
    const float* rewW = (const float*)d_in[14];
    const float* conW = (const float*)d_in[15];
    const float* conB = (const float*)d_in[16];

    rssm_fused<<<NB / 8, 256, 0, stream>>>(x, a, h0, gumb, encW, encB, Wih, Whh,
                                           bih, bhh, decW, decB, dynW, dynB,
                                           rewW, conW, conB, (float*)d_out);
}

// Round 4
// 1014.220 us; speedup vs baseline: 1.1743x; 1.1743x over previous
//
#include <hip/hip_runtime.h>

// RSSM fused forward — R3: wave-independent restructure.
// 512 blocks x 256 threads; each wave owns ONE batch element for all 256 steps.
// 2 blocks/CU (LDS 67.7KB) -> 8 waves/CU = 2 waves/SIMD; NO barriers in t-loop
// (h exchange is wave-private LDS; z sparse state lives in registers via shuffles).
// Weight rows in LDS at ODD strides (37/45/97), scalar ds_read_b32 with
// compile-time offsets -> conflict-free for 64-distinct-row reads.
// Lane l (0..63): enc/dyn row l; GRU rowA = l (r-rows 0..31 / z-rows 32..63),
// rowB = 64 + (l&31) (n-row, computed redundantly by both halves, no divergence).
// Straight-through z is exactly 8-sparse (off-hot positions are IEEE +0).

#define TT 256
#define NB 2048
#define HH 32
#define ZD 64
#define XDm 10
#define ADm 4

// LDS strides (floats) — odd => 64 distinct rows span all 32 banks 2x (free)
#define SWHH_S 37
#define SWIH_S 97   // transposed [col][row]
#define SENC_S 45
#define SDYN_S 37
#define SDEC_S 97
#define SH_S   40

// output offsets (floats) in return order: x_logits, r_loc, c_logits, zpl, zpo
#define OFF_X   0ul
#define OFF_R   5242880ul
#define OFF_C   5767168ul
#define OFF_ZPL 6291456ul
#define OFF_ZPO 39845888ul

__device__ __forceinline__ float sigmoid_f(float v) { return 1.f / (1.f + __expf(-v)); }
__device__ __forceinline__ void nt_store(float* p, float v) { __builtin_nontemporal_store(v, p); }

extern "C" __global__ void __launch_bounds__(256, 2)
rssm_fused(const float* __restrict__ x, const float* __restrict__ a,
           const float* __restrict__ h0, const float* __restrict__ gum,
           const float* __restrict__ encW, const float* __restrict__ encB,
           const float* __restrict__ Wih, const float* __restrict__ Whh,
           const float* __restrict__ bih, const float* __restrict__ bhh,
           const float* __restrict__ decW, const float* __restrict__ decB,
           const float* __restrict__ dynW, const float* __restrict__ dynB,
           const float* __restrict__ rewW, const float* __restrict__ conW,
           const float* __restrict__ conB, float* __restrict__ out)
{
    __shared__ float sWhh[96 * SWHH_S];
    __shared__ float sWih[68 * SWIH_S];          // transposed: [col][row]
    __shared__ float sEnc[64 * SENC_S];
    __shared__ float sDyn[64 * SDYN_S];
    __shared__ float sDec[10 * SDEC_S];
    __shared__ float sBih[96], sBhh[96], sEncB[64], sDynB[64], sDecB[16];
    __shared__ float sRew[32], sCon[32], sConB;
    __shared__ __align__(16) float sH[4 * SH_S]; // per-wave h exchange (wave-private)

    const int tid = threadIdx.x;

    // ---- stage weights into LDS (cooperative, once) ----
    for (int i = tid; i < 96 * HH; i += 256) { int j = i >> 5, k = i & 31; sWhh[j * SWHH_S + k] = Whh[i]; }
    for (int i = tid; i < 96 * 68; i += 256) { int j = i / 68, c = i - j * 68; sWih[c * SWIH_S + j] = Wih[i]; }
    for (int i = tid; i < 64 * 42; i += 256) { int j = i / 42, c = i - j * 42; sEnc[j * SENC_S + c] = encW[i]; }
    for (int i = tid; i < 64 * HH; i += 256) { int j = i >> 5, k = i & 31; sDyn[j * SDYN_S + k] = dynW[i]; }
    for (int i = tid; i < 10 * 96; i += 256) { int j = i / 96, c = i - j * 96; sDec[j * SDEC_S + c] = decW[i]; }
    if (tid < 96) { sBih[tid] = bih[tid]; sBhh[tid] = bhh[tid]; }
    if (tid >= 96 && tid < 160) { sEncB[tid - 96] = encB[tid - 96]; sDynB[tid - 96] = dynB[tid - 96]; }
    if (tid >= 160 && tid < 170) sDecB[tid - 160] = decB[tid - 160];
    if (tid >= 192 && tid < 224) sRew[tid - 192] = rewW[tid - 192];
    if (tid >= 224) sCon[tid - 224] = conW[tid - 224];
    if (tid == 170) sConB = conB[0];

    const int wv  = tid >> 6;       // wave in block = element slot 0..3
    const int l   = tid & 63;       // lane
    const int j32 = l & 31;
    const int grp = l >> 3;         // softmax group 0..7
    const int gl  = l & 7;          // class within group
    const int n   = blockIdx.x * 4 + wv;

    __syncthreads();   // weights ready — the ONLY block barrier

    // ---- per-wave h0 init (wave-private LDS broadcast) ----
    float h[HH], h_own;
    {
        float h0v = 0.f;
        if (l < HH) { h0v = h0[(size_t)n * HH + l]; sH[wv * SH_S + l] = h0v; }
#pragma unroll
        for (int k = 0; k < HH; k += 4) {
            float4 v = *(const float4*)&sH[wv * SH_S + k];
            h[k] = v.x; h[k + 1] = v.y; h[k + 2] = v.z; h[k + 3] = v.w;
        }
        h_own = h0v;
    }

    const float* xb = x + (size_t)n * XDm;
    const float* ab = a + (size_t)n * ADm;

    // ---- prime input pipeline: t=0 ----
    float et[XDm], ap[ADm], gv;
    float sv[8]; int si[8];
#pragma unroll
    for (int s = 0; s < 8; ++s) { sv[s] = 0.f; si[s] = 0; }
#pragma unroll
    for (int m = 0; m < XDm; ++m) et[m] = xb[m];
    gv = gum[(size_t)n * ZD + l];
#pragma unroll
    for (int m = 0; m < ADm; ++m) ap[m] = 0.f;

#pragma unroll 1
    for (int t = 0; t < TT; ++t) {
        // ---- prefetch t+1 inputs (hides HBM/L2 latency under this iteration) ----
        float etn[XDm], apn[ADm], gvn = 0.f;
        if (t + 1 < TT) {
            const float* xp = xb + (size_t)(t + 1) * (NB * XDm);
#pragma unroll
            for (int m = 0; m < XDm; ++m) etn[m] = xp[m];
            gvn = gum[((size_t)(t + 1) * NB + n) * ZD + l];
            const float* app = ab + (size_t)t * (NB * ADm);   // a[t] feeds GRU at t+1
#pragma unroll
            for (int m = 0; m < ADm; ++m) apn[m] = app[m];
        } else {
#pragma unroll
            for (int m = 0; m < XDm; ++m) etn[m] = 0.f;
#pragma unroll
            for (int m = 0; m < ADm; ++m) apn[m] = 0.f;
        }

        // ---- GRU step (t>=1): rowA = l (r/z rows), rowB = 64+(l&31) (n row) ----
        if (t > 0) {
            const float* wA = &sWhh[l * SWHH_S];
            const float* wB = &sWhh[(64 + j32) * SWHH_S];
            float accA = 0.f, accB = 0.f;
#pragma unroll
            for (int k = 0; k < HH; ++k) {
                accA = fmaf(wA[k], h[k], accA);
                accB = fmaf(wB[k], h[k], accB);
            }
            float giA = 0.f, giB = 0.f;
#pragma unroll
            for (int s = 0; s < 8; ++s) {          // sparse z part, ascending cols
                int   c = 8 * s + si[s];
                float v = sv[s];
                const float* wc = &sWih[c * SWIH_S];
                giA = fmaf(wc[l], v, giA);
                giB = fmaf(wc[64 + j32], v, giB);
            }
#pragma unroll
            for (int m = 0; m < ADm; ++m) {        // action part
                const float* wc = &sWih[(64 + m) * SWIH_S];
                giA = fmaf(wc[l], ap[m], giA);
                giB = fmaf(wc[64 + j32], ap[m], giB);
            }
            giA += sBih[l];        float ghA = accA + sBhh[l];
            giB += sBih[64 + j32]; float ghB = accB + sBhh[64 + j32];
            float sA = sigmoid_f(giA + ghA);       // r_j on l<32, z_j on l>=32
            float zj = __shfl(sA, l | 32);         // z_j delivered to all lanes
            float ng = tanhf(giB + sA * ghB);      // valid where sA==r (l<32)
            float hn = (1.f - zj) * ng + zj * h_own;
            if (l < HH) sH[wv * SH_S + l] = hn;
#pragma unroll
            for (int k = 0; k < HH; k += 4) {
                float4 v = *(const float4*)&sH[wv * SH_S + k];
                h[k] = v.x; h[k + 1] = v.y; h[k + 2] = v.z; h[k + 3] = v.w;
            }
            h_own = hn;
        }

        // ---- encoder row l: zl[l] = enc_W[l] . [h ; e_t] + enc_b[l] ----
        float z;
        {
            const float* we = &sEnc[l * SENC_S];
            float acc = 0.f;
#pragma unroll
            for (int k = 0; k < HH; ++k) acc = fmaf(we[k], h[k], acc);
#pragma unroll
            for (int m = 0; m < XDm; ++m) acc = fmaf(we[HH + m], et[m], acc);
            z = acc + sEncB[l];
        }

        // ---- straight-through gumbel sample, 8-lane groups (xor 1/2/4 tree) ----
        float mx = z;
#pragma unroll
        for (int d = 1; d < 8; d <<= 1) mx = fmaxf(mx, __shfl_xor(mx, d));
        float key = z + gv; int ki = gl;
#pragma unroll
        for (int d = 1; d < 8; d <<= 1) {
            float ok = __shfl_xor(key, d); int oi = __shfl_xor(ki, d);
            if (ok > key || (ok == key && oi < ki)) { key = ok; ki = oi; }
        }
        float p = __expf(z - mx);
        float ssum = p;
#pragma unroll
        for (int d = 1; d < 8; d <<= 1) ssum += __shfl_xor(ssum, d);
        float pk  = __shfl(p, (grp << 3) + ki) / ssum;   // prob at argmax slot
        float val = pk + (1.f - pk);
        // gather all 8 groups' (idx, val) into registers (group-uniform sources)
#pragma unroll
        for (int s = 0; s < 8; ++s) {
            sv[s] = __shfl(val, s << 3);
            si[s] = __shfl(ki,  s << 3);
        }

        // ---- z prior logits out (coalesced 256B per wave) ----
        nt_store(&out[OFF_ZPL + ((size_t)t * NB + n) * ZD + l], z);

        // ---- dynamics head row l ----
        {
            const float* wd = &sDyn[l * SDYN_S];
            float acc = 0.f;
#pragma unroll
            for (int k = 0; k < HH; ++k) acc = fmaf(wd[k], h[k], acc);
            nt_store(&out[OFF_ZPO + ((size_t)t * NB + n) * ZD + l], acc + sDynB[l]);
        }

        // ---- decoder / reward / continue heads ----
        if (l < XDm) {
            const float* dw = &sDec[l * SDEC_S];
            float acc = 0.f;
#pragma unroll
            for (int k = 0; k < HH; ++k) acc = fmaf(dw[k], h[k], acc);
#pragma unroll
            for (int s = 0; s < 8; ++s)
                acc = fmaf(dw[HH + 8 * s + si[s]], sv[s], acc);
            acc += sDecB[l];
            nt_store(&out[OFF_X + ((size_t)t * NB + n) * XDm + l], acc);
        } else if (l >= 10 && l < 12) {
            const float* hw = (l == 10) ? sRew : sCon;
            float acc = 0.f;
#pragma unroll
            for (int k = 0; k < HH; ++k) acc = fmaf(hw[k], h[k], acc);
            if (l == 11) acc += sConB;
            size_t off = (l == 10) ? OFF_R : OFF_C;
            nt_store(&out[off + (size_t)t * NB + n], acc);
        }

        // ---- rotate input pipeline ----
#pragma unroll
        for (int m = 0; m < XDm; ++m) et[m] = etn[m];
#pragma unroll
        for (int m = 0; m < ADm; ++m) ap[m] = apn[m];
        gv = gvn;
    }
}

extern "C" void kernel_launch(void* const* d_in, const int* in_sizes, int n_in,
                              void* d_out, int out_size, void* d_ws, size_t ws_size,
                              hipStream_t stream) {
    const float* x    = (const float*)d_in[0];
    const float* a    = (const float*)d_in[1];
    const float* h0   = (const float*)d_in[2];
    const float* gumb = (const float*)d_in[3];
    const float* encW = (const float*)d_in[4];
    const float* encB = (const float*)d_in[5];
    const float* Wih  = (const float*)d_in[6];
    const float* Whh  = (const float*)d_in[7];
    const float* bih  = (const float*)d_in[8];
    const float* bhh  = (const float*)d_in[9];
    const float* decW = (const float*)d_in[10];
    const float* decB = (const float*)d_in[11];
    const float* dynW = (const float*)d_in[12];
    const float* dynB = (const float*)d_in[13];
    const float* rewW = (const float*)d_in[14];
    const float* conW = (const float*)d_in[15];
    const float* conB = (const float*)d_in[16];

    rssm_fused<<<NB / 4, 256, 0, stream>>>(x, a, h0, gumb, encW, encB, Wih, Whh,
                                           bih, bhh, decW, decB, dynW, dynB,
                                           rewW, conW, conB, (float*)d_out);
}